// Round 8
// baseline (193.008 us; speedup 1.0000x reference)
//
#include <hip/hip_runtime.h>
#include <math.h>

// ---------------------------------------------------------------------------
// Decoder block: B=2, S=2048, D=512, H=8, DK=64, FF=2048.
// Round 8: permuted-key P layout so softmax P packs via v_cvt_pk_bf16_f32
// (pi(f*16+j)=j*4+f applied to BOTH P and Vt -> PV invariant); proj/FF2 in
// bf16; LN residual input bf16. Fixed-max softmax; KV-split=2; dbuf K/V.
// LDS tiles: [rows][64] bf16, XOR-16B swizzle (phys_short = col ^ ((row&7)*8)).
// ---------------------------------------------------------------------------

typedef __attribute__((ext_vector_type(8))) short short8;   // 8 bf16
typedef __attribute__((ext_vector_type(4))) float f32x4;

#define MFMA16(a, b, c) __builtin_amdgcn_mfma_f32_16x16x32_bf16((a), (b), (c), 0, 0, 0)

__device__ __forceinline__ unsigned short f2bf(float f) {
    unsigned int u = __float_as_uint(f);
    u += 0x7fffu + ((u >> 16) & 1u);          // RNE
    return (unsigned short)(u >> 16);
}
__device__ __forceinline__ float bf2f(unsigned short h) {
    return __uint_as_float(((unsigned int)h) << 16);
}
__device__ __forceinline__ void g2l16(const void* g, void* l) {
    __builtin_amdgcn_global_load_lds(
        (const __attribute__((address_space(1))) unsigned int*)g,
        (__attribute__((address_space(3))) unsigned int*)l, 16, 0, 0);
}
// swizzled short-index within a [rows][64]-short LDS tile
__device__ __forceinline__ int swz(int row, int col) {
    return row * 64 + (col ^ ((row & 7) * 8));
}
// XCD-chunked work remap (bijective: all grids are multiples of 8)
__device__ __forceinline__ void xcd_remap(int& bx, int& by, int& bz) {
    const int gx = gridDim.x, gy = gridDim.y;
    const int nwg = gx * gy * gridDim.z;
    const int flat = blockIdx.x + gx * (blockIdx.y + gy * blockIdx.z);
    const int s = (flat & 7) * (nwg >> 3) + (flat >> 3);
    bx = s % gx; const int t = s / gx; by = t % gy; bz = t / gy;
}

// ---------------- bf16 GEMM: C[M,N] = A[M,K] @ Bt[N,K]^T + bias ------------
// 4 waves, double-buffered global_load_lds.
// MODE: 0 = f32 out; 3 = bf16+ReLU; 4 = bf16.
template <int BM, int BN, int MODE>
__global__ __launch_bounds__(256, (BM == 64) ? 4 : (BN == 128 ? 2 : 3))
void gemm_bf16(
    const unsigned short* __restrict__ A, const unsigned short* __restrict__ Bt,
    const float* __restrict__ bias, float* __restrict__ Cf,
    unsigned short* __restrict__ O1,
    int M, int N, int K)
{
    __shared__ unsigned short As[2][BM * 64];
    __shared__ unsigned short Bs[2][BN * 64];
    const int tid = threadIdx.x, wv = tid >> 6, lane = tid & 63;
    const int l15 = lane & 15, l4 = lane >> 4;
    int bx, by, bz; xcd_remap(bx, by, bz);
    const int bm = by * BM, bn = bx * BN;
    constexpr int MI = (BM == 64) ? 1 : (BN == 128 ? 4 : 2);
    constexpr int AJ = (BM == 64) ? 2 : 4;
    constexpr int BJ = (BN == 128) ? 4 : 2;
    const int wrow = (BM == 64) ? wv * 16 : (BN == 128 ? (wv >> 1) * 64 : wv * 32);
    const int wcol = (BN == 128) ? (wv & 1) * 64 : 0;
    const int aw = (BM == 64) ? wv * 16 : wv * 32;   // A-staging base row
    const int bw = (BN == 128) ? wv * 32 : wv * 16;  // B-staging base row

    f32x4 acc[MI][4];
    #pragma unroll
    for (int i = 0; i < MI; ++i)
        #pragma unroll
        for (int j = 0; j < 4; ++j) acc[i][j] = (f32x4){0.f, 0.f, 0.f, 0.f};

    const int srow = lane >> 3;                       // 0..7 within 8-row chunk
    const int sch  = (lane & 7) ^ srow;               // inverse-swizzled 16B chunk
    const unsigned short* Asrc = A + (size_t)(bm + aw + srow) * K + sch * 8;
    const unsigned short* Bsrc = Bt + (size_t)(bn + bw + srow) * K + sch * 8;

    auto stage = [&](int buf, int k0) {
        #pragma unroll
        for (int j = 0; j < AJ; ++j)
            g2l16(Asrc + (size_t)j * 8 * K + k0, &As[buf][(aw + j * 8) * 64]);
        #pragma unroll
        for (int j = 0; j < BJ; ++j)
            g2l16(Bsrc + (size_t)j * 8 * K + k0, &Bs[buf][(bw + j * 8) * 64]);
    };

    stage(0, 0);
    __syncthreads();
    int cur = 0;
    for (int k0 = 0; k0 < K; k0 += 64) {
        if (k0 + 64 < K) stage(cur ^ 1, k0 + 64);
        #pragma unroll
        for (int kk = 0; kk < 2; ++kk) {
            const int kc = kk * 32 + l4 * 8;
            short8 af[MI], bfr[4];
            #pragma unroll
            for (int mi = 0; mi < MI; ++mi)
                af[mi] = *(const short8*)&As[cur][swz(wrow + mi * 16 + l15, kc)];
            #pragma unroll
            for (int nf = 0; nf < 4; ++nf)
                bfr[nf] = *(const short8*)&Bs[cur][swz(wcol + nf * 16 + l15, kc)];
            __builtin_amdgcn_s_setprio(1);
            #pragma unroll
            for (int mi = 0; mi < MI; ++mi)
                #pragma unroll
                for (int nf = 0; nf < 4; ++nf)
                    acc[mi][nf] = MFMA16(af[mi], bfr[nf], acc[mi][nf]);
            __builtin_amdgcn_s_setprio(0);
        }
        __syncthreads();
        cur ^= 1;
    }

    #pragma unroll
    for (int nf = 0; nf < 4; ++nf) {
        const int n = bn + wcol + nf * 16 + l15;
        const float bv = bias[n];
        #pragma unroll
        for (int mi = 0; mi < MI; ++mi) {
            const int m0 = bm + wrow + mi * 16 + l4 * 4;
            #pragma unroll
            for (int r = 0; r < 4; ++r) {
                float v = acc[mi][nf][r] + bv;
                size_t idx = (size_t)(m0 + r) * N + n;
                if (MODE == 0)      Cf[idx] = v;
                else if (MODE == 3) O1[idx] = f2bf(fmaxf(v, 0.f));
                else                O1[idx] = f2bf(v);
            }
        }
    }
}

// ---------------- merged QKV GEMM (3 jobs in one launch) -------------------
struct QKVArgs {
    const unsigned short* A[3];
    const unsigned short* Bt[3];
    const float* bias[3];
    unsigned short* O1[3];
    int mode[3];      // 4 = plain bf16 out; 2 = transposed+key-permuted Vt out
};
__global__ __launch_bounds__(256, 3) void qkv_gemm(QKVArgs ja)
{
    __shared__ unsigned short As[2][128 * 64];
    __shared__ unsigned short Bs[2][64 * 64];
    const int tid = threadIdx.x, wv = tid >> 6, lane = tid & 63;
    const int l15 = lane & 15, l4 = lane >> 4;
    int bx, by, bz; xcd_remap(bx, by, bz);
    const int bm = by * 128, bn = bx * 64;
    const unsigned short* A  = ja.A[bz];
    const unsigned short* Bt = ja.Bt[bz];
    const int mode = ja.mode[bz];

    f32x4 acc[2][4];
    #pragma unroll
    for (int i = 0; i < 2; ++i)
        #pragma unroll
        for (int j = 0; j < 4; ++j) acc[i][j] = (f32x4){0.f, 0.f, 0.f, 0.f};

    const int srow = lane >> 3, sch = (lane & 7) ^ srow;
    const unsigned short* Asrc = A + (size_t)(bm + wv * 32 + srow) * 512 + sch * 8;
    const unsigned short* Bsrc = Bt + (size_t)(bn + wv * 16 + srow) * 512 + sch * 8;

    auto stage = [&](int buf, int k0) {
        #pragma unroll
        for (int j = 0; j < 4; ++j)
            g2l16(Asrc + (size_t)j * 8 * 512 + k0, &As[buf][(wv * 32 + j * 8) * 64]);
        #pragma unroll
        for (int j = 0; j < 2; ++j)
            g2l16(Bsrc + (size_t)j * 8 * 512 + k0, &Bs[buf][(wv * 16 + j * 8) * 64]);
    };

    stage(0, 0);
    __syncthreads();
    int cur = 0;
    for (int k0 = 0; k0 < 512; k0 += 64) {
        if (k0 + 64 < 512) stage(cur ^ 1, k0 + 64);
        #pragma unroll
        for (int kk = 0; kk < 2; ++kk) {
            const int kc = kk * 32 + l4 * 8;
            short8 af[2], bfr[4];
            af[0] = *(const short8*)&As[cur][swz(wv * 32 + l15, kc)];
            af[1] = *(const short8*)&As[cur][swz(wv * 32 + 16 + l15, kc)];
            #pragma unroll
            for (int nf = 0; nf < 4; ++nf)
                bfr[nf] = *(const short8*)&Bs[cur][swz(nf * 16 + l15, kc)];
            __builtin_amdgcn_s_setprio(1);
            #pragma unroll
            for (int mi = 0; mi < 2; ++mi)
                #pragma unroll
                for (int nf = 0; nf < 4; ++nf)
                    acc[mi][nf] = MFMA16(af[mi], bfr[nf], acc[mi][nf]);
            __builtin_amdgcn_s_setprio(0);
        }
        __syncthreads();
        cur ^= 1;
    }

    #pragma unroll
    for (int nf = 0; nf < 4; ++nf) {
        const int n = bn + nf * 16 + l15;
        const float bv = ja.bias[bz][n];
        #pragma unroll
        for (int mi = 0; mi < 2; ++mi) {
            const int m0 = bm + wv * 32 + mi * 16 + l4 * 4;
            if (mode == 2) {
                // Vt with within-64-key permutation pi(f*16+j) = j*4+f
                const int hh = n >> 6, dd = n & 63, bb = m0 >> 11;
                const int key = m0 & 2047;
                const int f = (key & 63) >> 4, j0 = key & 15;
                const size_t basevt = (((size_t)bb * 8 + hh) * 64 + dd) * 2048
                                    + (key & ~63) + f;
                #pragma unroll
                for (int r = 0; r < 4; ++r)
                    ja.O1[bz][basevt + (size_t)(j0 + r) * 4] = f2bf(acc[mi][nf][r] + bv);
            } else {
                #pragma unroll
                for (int r = 0; r < 4; ++r)
                    ja.O1[bz][(size_t)(m0 + r) * 512 + n] = f2bf(acc[mi][nf][r] + bv);
            }
        }
    }
}

// ---------------- MFMA flash attention, fixed-max, KV-split=2 --------------
// Qb/Kb: [B*S, 512] bf16 head-major cols. Vt: [b][h][d][2048] bf16,
// key-permuted within 64-tiles. Partials: PO{0,1}[4096][512] f32; PL f32.
// Grid (S/64, B*H, 2), block 256 (4 waves x 16 q-rows).
// P packed via v_cvt_pk_bf16_f32 into permuted-key PS (matches Vt layout).
__global__ __launch_bounds__(256, 2) void attn_mfma(
    const unsigned short* __restrict__ Qb, const unsigned short* __restrict__ Kb,
    const unsigned short* __restrict__ Vt,
    float* __restrict__ PO0, float* __restrict__ PO1, float* __restrict__ PL)
{
    __shared__ unsigned short KH[2][64 * 64];
    __shared__ unsigned short VT[2][64 * 64];   // [d][key-permuted]
    __shared__ unsigned short PS[64 * 64];      // P scratch (wave-private rows)

    const int tid = threadIdx.x, wv = tid >> 6, lane = tid & 63;
    const int l15 = lane & 15, l4 = lane >> 4;
    int bx, by, bz; xcd_remap(bx, by, bz);
    const int bh = by, b = bh >> 3, h = bh & 7;
    const int q0 = bx * 64;
    const int srow = lane >> 3;
    const int sch  = (lane & 7) ^ srow;
    const int kt0 = bz * 16, kt1 = kt0 + 16;

    // Q fragments direct from global (one-time strided gather)
    short8 qh[2];
    {
        const size_t qrow = (size_t)(b * 2048 + q0 + wv * 16 + l15) * 512 + h * 64;
        qh[0] = *(const short8*)(Qb + qrow + l4 * 8);
        qh[1] = *(const short8*)(Qb + qrow + 32 + l4 * 8);
    }

    const unsigned short* k_src  = Kb + (size_t)(b * 2048 + wv * 16 + srow) * 512 + h * 64 + sch * 8;
    const unsigned short* vt_src = Vt + (size_t)(bh * 64 + wv * 16 + srow) * 2048 + sch * 8;

    auto stageKV = [&](int buf, int kt) {
        const size_t k0 = (size_t)kt * 64;
        #pragma unroll
        for (int j = 0; j < 2; ++j) {
            g2l16(k_src + (k0 + j * 8) * 512, &KH[buf][(wv * 16 + j * 8) * 64]);
            g2l16(vt_src + k0 + (size_t)j * 8 * 2048, &VT[buf][(wv * 16 + j * 8) * 64]);
        }
    };

    f32x4 o[4], lacc;
    #pragma unroll
    for (int i = 0; i < 4; ++i) o[i] = (f32x4){0.f, 0.f, 0.f, 0.f};
    lacc = (f32x4){0.f, 0.f, 0.f, 0.f};

    const short one_s = (short)(l15 == 0 ? 0x3F80 : 0);     // bf16 1.0 in col 0
    const short8 oneb = {one_s, one_s, one_s, one_s, one_s, one_s, one_s, one_s};

    stageKV(0, kt0);
    __syncthreads();
    int cur = 0;
    for (int kt = kt0; kt < kt1; ++kt) {
        if (kt + 1 < kt1) stageKV(cur ^ 1, kt + 1);   // prefetch under compute

        // QK^T: wave's 16 q-rows x 64 keys (plain bf16)
        f32x4 s[4];
        __builtin_amdgcn_s_setprio(1);
        #pragma unroll
        for (int f = 0; f < 4; ++f) {
            s[f] = (f32x4){0.f, 0.f, 0.f, 0.f};
            #pragma unroll
            for (int kk = 0; kk < 2; ++kk) {
                short8 kbf = *(const short8*)&KH[cur][swz(f * 16 + l15, kk * 32 + l4 * 8)];
                s[f] = MFMA16(qh[kk], kbf, s[f]);
            }
        }
        __builtin_amdgcn_s_setprio(0);

        // P = exp(floor(s/8)), fixed max 0; packed pairs into permuted-key PS:
        // key f*16+l15 sits at position l15*4+f -> 2x cvt_pk + 1x b64 write/row
        #pragma unroll
        for (int r = 0; r < 4; ++r) {
            float p0 = __expf(floorf(s[0][r] * 0.125f));
            float p1 = __expf(floorf(s[1][r] * 0.125f));
            float p2 = __expf(floorf(s[2][r] * 0.125f));
            float p3 = __expf(floorf(s[3][r] * 0.125f));
            unsigned u0, u1;
            asm("v_cvt_pk_bf16_f32 %0, %1, %2" : "=v"(u0) : "v"(p0), "v"(p1));
            asm("v_cvt_pk_bf16_f32 %0, %1, %2" : "=v"(u1) : "v"(p2), "v"(p3));
            *(uint2*)&PS[swz(wv * 16 + l4 * 4 + r, l15 * 4)] = (uint2){u0, u1};
        }

        short8 pa[2];
        pa[0] = *(const short8*)&PS[swz(wv * 16 + l15, l4 * 8)];
        pa[1] = *(const short8*)&PS[swz(wv * 16 + l15, 32 + l4 * 8)];

        __builtin_amdgcn_s_setprio(1);
        lacc = MFMA16(pa[0], oneb, lacc);     // row-sum via ones column
        lacc = MFMA16(pa[1], oneb, lacc);
        #pragma unroll
        for (int df = 0; df < 4; ++df) {
            #pragma unroll
            for (int kk = 0; kk < 2; ++kk) {
                short8 vb = *(const short8*)&VT[cur][swz(df * 16 + l15, kk * 32 + l4 * 8)];
                o[df] = MFMA16(pa[kk], vb, o[df]);
            }
        }
        __builtin_amdgcn_s_setprio(0);
        __syncthreads();                      // drain prefetch + readers done
        cur ^= 1;
    }

    // epilogue: raw partial o (f32) + partial l
    float* PO = bz ? PO1 : PO0;
    #pragma unroll
    for (int df = 0; df < 4; ++df)
        #pragma unroll
        for (int r = 0; r < 4; ++r)
            PO[(size_t)(b * 2048 + q0 + wv * 16 + l4 * 4 + r) * 512 + h * 64 + df * 16 + l15]
                = o[df][r];
    if (l15 == 0) {
        #pragma unroll
        for (int r = 0; r < 4; ++r)
            PL[(bz * 16 + bh) * 2048 + q0 + wv * 16 + l4 * 4 + r] = lacc[r];
    }
}

// ---------------- combine: Ob = (po0+po1)/(l0+l1), bf16 --------------------
__global__ __launch_bounds__(256) void attn_combine(
    const float* __restrict__ po0, const float* __restrict__ po1,
    const float* __restrict__ pl, unsigned short* __restrict__ Ob)
{
    const size_t i = ((size_t)blockIdx.x * 256 + threadIdx.x) * 8;  // over 4096*512
    const int row = (int)(i >> 9), col = (int)(i & 511);
    const int b = row >> 11, q = row & 2047, h = col >> 6;
    const int bh = b * 8 + h;
    const float inv = 1.f / (pl[bh * 2048 + q] + pl[(16 + bh) * 2048 + q]);
    float4 a0 = *(const float4*)(po0 + i), a1 = *(const float4*)(po0 + i + 4);
    float4 c0 = *(const float4*)(po1 + i), c1 = *(const float4*)(po1 + i + 4);
    uint4 u;
    u.x = (unsigned)f2bf((a0.x + c0.x) * inv) | ((unsigned)f2bf((a0.y + c0.y) * inv) << 16);
    u.y = (unsigned)f2bf((a0.z + c0.z) * inv) | ((unsigned)f2bf((a0.w + c0.w) * inv) << 16);
    u.z = (unsigned)f2bf((a1.x + c1.x) * inv) | ((unsigned)f2bf((a1.y + c1.y) * inv) << 16);
    u.w = (unsigned)f2bf((a1.z + c1.z) * inv) | ((unsigned)f2bf((a1.w + c1.w) * inv) << 16);
    *(uint4*)(Ob + i) = u;
}

// ---------------- fused residual add + LayerNorm (D=512) -------------------
// X: residual branch; R: projection branch. Types per template flags.
template <bool XBF, bool RBF, bool OUTF, bool OUTB>
__global__ __launch_bounds__(256) void add_ln(
    const void* __restrict__ Xv, const void* __restrict__ Rv,
    const float* __restrict__ g, const float* __restrict__ beta,
    float* __restrict__ OutF, unsigned short* __restrict__ OutB)
{
    const int row = blockIdx.x * 4 + (threadIdx.x >> 6);
    const int lane = threadIdx.x & 63;
    const int c0 = lane * 8;
    float xx[8], rr[8], v[8];
    if (XBF) {
        const unsigned short* xr = (const unsigned short*)Xv + (size_t)row * 512 + c0;
        uint4 u = *(const uint4*)xr;
        xx[0] = bf2f(u.x & 0xffff); xx[1] = bf2f(u.x >> 16);
        xx[2] = bf2f(u.y & 0xffff); xx[3] = bf2f(u.y >> 16);
        xx[4] = bf2f(u.z & 0xffff); xx[5] = bf2f(u.z >> 16);
        xx[6] = bf2f(u.w & 0xffff); xx[7] = bf2f(u.w >> 16);
    } else {
        const float* xr = (const float*)Xv + (size_t)row * 512 + c0;
        float4 a0 = *(const float4*)xr, a1 = *(const float4*)(xr + 4);
        xx[0] = a0.x; xx[1] = a0.y; xx[2] = a0.z; xx[3] = a0.w;
        xx[4] = a1.x; xx[5] = a1.y; xx[6] = a1.z; xx[7] = a1.w;
    }
    if (RBF) {
        const unsigned short* xr = (const unsigned short*)Rv + (size_t)row * 512 + c0;
        uint4 u = *(const uint4*)xr;
        rr[0] = bf2f(u.x & 0xffff); rr[1] = bf2f(u.x >> 16);
        rr[2] = bf2f(u.y & 0xffff); rr[3] = bf2f(u.y >> 16);
        rr[4] = bf2f(u.z & 0xffff); rr[5] = bf2f(u.z >> 16);
        rr[6] = bf2f(u.w & 0xffff); rr[7] = bf2f(u.w >> 16);
    } else {
        const float* xr = (const float*)Rv + (size_t)row * 512 + c0;
        float4 a0 = *(const float4*)xr, a1 = *(const float4*)(xr + 4);
        rr[0] = a0.x; rr[1] = a0.y; rr[2] = a0.z; rr[3] = a0.w;
        rr[4] = a1.x; rr[5] = a1.y; rr[6] = a1.z; rr[7] = a1.w;
    }
    float s = 0.f, s2 = 0.f;
    #pragma unroll
    for (int j = 0; j < 8; ++j) {
        v[j] = xx[j] + rr[j];
        s += v[j]; s2 += v[j] * v[j];
    }
    #pragma unroll
    for (int off = 1; off < 64; off <<= 1) {
        s  += __shfl_xor(s, off);
        s2 += __shfl_xor(s2, off);
    }
    const float mean = s * (1.f / 512.f);
    const float var = s2 * (1.f / 512.f) - mean * mean;
    const float rs = 1.f / sqrtf(var + 1e-5f);
    float ovals[8];
    const float* gg = g + c0; const float* bb = beta + c0;
    #pragma unroll
    for (int j = 0; j < 8; ++j) ovals[j] = (v[j] - mean) * rs * gg[j] + bb[j];
    if (OUTF) {
        float* po = OutF + (size_t)row * 512 + c0;
        *(float4*)po = (float4){ovals[0], ovals[1], ovals[2], ovals[3]};
        *(float4*)(po + 4) = (float4){ovals[4], ovals[5], ovals[6], ovals[7]};
    }
    if (OUTB) {
        uint4 u;
        u.x = (unsigned)f2bf(ovals[0]) | ((unsigned)f2bf(ovals[1]) << 16);
        u.y = (unsigned)f2bf(ovals[2]) | ((unsigned)f2bf(ovals[3]) << 16);
        u.z = (unsigned)f2bf(ovals[4]) | ((unsigned)f2bf(ovals[5]) << 16);
        u.w = (unsigned)f2bf(ovals[6]) | ((unsigned)f2bf(ovals[7]) << 16);
        *(uint4*)(OutB + (size_t)row * 512 + c0) = u;
    }
}

// ---------------- merged prep: conv x/enc -> bf16 + weight transposes ------
struct WTJobs {
    const float* src[10];
    unsigned short* dst[10];
    int K[10], N[10];
    int cum[11];
};
__global__ __launch_bounds__(256) void prep(
    const float* __restrict__ X, const float* __restrict__ E,
    unsigned short* __restrict__ Xb, unsigned short* __restrict__ Eb, WTJobs jb)
{
    __shared__ float T[32][33];
    const int bid = blockIdx.x;
    if (bid < 2048) {
        size_t i = ((size_t)bid * 256 + threadIdx.x) * 8;
        const float* src; unsigned short* dst; size_t off;
        if (i < 2097152) { src = X; dst = Xb; off = i; }
        else             { src = E; dst = Eb; off = i - 2097152; }
        float4 a = *(const float4*)(src + off), c = *(const float4*)(src + off + 4);
        uint4 u;
        u.x = (unsigned)f2bf(a.x) | ((unsigned)f2bf(a.y) << 16);
        u.y = (unsigned)f2bf(a.z) | ((unsigned)f2bf(a.w) << 16);
        u.z = (unsigned)f2bf(c.x) | ((unsigned)f2bf(c.y) << 16);
        u.w = (unsigned)f2bf(c.z) | ((unsigned)f2bf(c.w) << 16);
        *(uint4*)(dst + off) = u;
        return;
    }
    int wb = bid - 2048;
    int z = 0;
    while (wb >= jb.cum[z + 1]) ++z;
    const int lt = wb - jb.cum[z];
    const int K = jb.K[z], N = jb.N[z];
    const int ntx = N >> 5;
    const int tx = lt % ntx, ty = lt / ntx;
    const int r = threadIdx.x >> 3, c4 = (threadIdx.x & 7) * 4;
    float4 a = *(const float4*)(jb.src[z] + (size_t)(ty * 32 + r) * N + tx * 32 + c4);
    T[r][c4] = a.x; T[r][c4 + 1] = a.y; T[r][c4 + 2] = a.z; T[r][c4 + 3] = a.w;
    __syncthreads();
    ushort4 o;
    o.x = f2bf(T[c4][r]); o.y = f2bf(T[c4 + 1][r]);
    o.z = f2bf(T[c4 + 2][r]); o.w = f2bf(T[c4 + 3][r]);
    *(ushort4*)(jb.dst[z] + (size_t)(tx * 32 + r) * K + ty * 32 + c4) = o;
}

// ---------------------------------------------------------------------------
extern "C" void kernel_launch(void* const* d_in, const int* in_sizes, int n_in,
                              void* d_out, int out_size, void* d_ws, size_t ws_size,
                              hipStream_t stream)
{
    const float* x   = (const float*)d_in[0];
    const float* enc = (const float*)d_in[1];
    // d_in[2], d_in[3]: masks — dead in the reference.
    const float* Wp[8] = {(const float*)d_in[4],  (const float*)d_in[6],
                          (const float*)d_in[8],  (const float*)d_in[10],
                          (const float*)d_in[12], (const float*)d_in[14],
                          (const float*)d_in[16], (const float*)d_in[18]};
    const float* sa_qb = (const float*)d_in[5],  *sa_kb = (const float*)d_in[7];
    const float* sa_vb = (const float*)d_in[9],  *sa_ob = (const float*)d_in[11];
    const float* ca_qb = (const float*)d_in[13], *ca_kb = (const float*)d_in[15];
    const float* ca_vb = (const float*)d_in[17], *ca_ob = (const float*)d_in[19];
    const float* ff_W1 = (const float*)d_in[20], *ff_b1 = (const float*)d_in[21];
    const float* ff_W2 = (const float*)d_in[22], *ff_b2 = (const float*)d_in[23];
    const float* ln0_g = (const float*)d_in[24], *ln0_b = (const float*)d_in[25];
    const float* ln1_g = (const float*)d_in[26], *ln1_b = (const float*)d_in[27];
    const float* ln2_g = (const float*)d_in[28], *ln2_b = (const float*)d_in[29];

    char* base = (char*)d_ws;
    const size_t MB = 1u << 20;
    unsigned short* wt    = (unsigned short*)(base + 0 * MB);   // 8 MB
    unsigned short* xb    = (unsigned short*)(base + 8 * MB);   // 4 MB (reused as x2b)
    unsigned short* encb  = (unsigned short*)(base + 12 * MB);  // 4 MB
    unsigned short* x1b   = (unsigned short*)(base + 16 * MB);  // 4 MB
    unsigned short* attnb = (unsigned short*)(base + 20 * MB);  // 4 MB
    unsigned short* vt    = (unsigned short*)(base + 24 * MB);  // 4 MB
    unsigned short* qb    = (unsigned short*)(base + 28 * MB);  // 4 MB
    unsigned short* kb    = (unsigned short*)(base + 32 * MB);  // 4 MB
    float*          pl    = (float*)(base + 36 * MB);           // 256 KB
    unsigned short* projb = (unsigned short*)(base + 44 * MB);  // 4 MB bf16
    float*          po0   = (float*)(base + 48 * MB);           // 8 MB f32
    unsigned short* ffb   = qb;                                 // 16 MB overlay (28..44)
    unsigned short* x2b   = xb;                                 // overlay
    float* po1 = (float*)d_out;                                 // free until final LN
    float* out = (float*)d_out;

    unsigned short* wtp[10];
    for (int i = 0; i < 8; ++i) wtp[i] = wt + (size_t)i * 262144;
    wtp[8] = wt + 8u * 262144;            // ff_W1t: [2048][512]
    wtp[9] = wt + 8u * 262144 + 1048576;  // ff_W2t: [512][2048]

    WTJobs jb;
    for (int i = 0; i < 8; ++i) { jb.src[i] = Wp[i]; jb.dst[i] = wtp[i]; jb.K[i] = 512; jb.N[i] = 512; }
    jb.src[8] = ff_W1; jb.dst[8] = wtp[8]; jb.K[8] = 512;  jb.N[8] = 2048;
    jb.src[9] = ff_W2; jb.dst[9] = wtp[9]; jb.K[9] = 2048; jb.N[9] = 512;
    jb.cum[0] = 0;
    for (int i = 0; i < 10; ++i)
        jb.cum[i + 1] = jb.cum[i] + (jb.N[i] >> 5) * (jb.K[i] >> 5);

    QKVArgs sa, ca;
    sa.A[0] = xb;  sa.Bt[0] = wtp[0]; sa.bias[0] = sa_qb; sa.O1[0] = qb; sa.mode[0] = 4;
    sa.A[1] = xb;  sa.Bt[1] = wtp[1]; sa.bias[1] = sa_kb; sa.O1[1] = kb; sa.mode[1] = 4;
    sa.A[2] = xb;  sa.Bt[2] = wtp[2]; sa.bias[2] = sa_vb; sa.O1[2] = vt; sa.mode[2] = 2;
    ca.A[0] = x1b;  ca.Bt[0] = wtp[4]; ca.bias[0] = ca_qb; ca.O1[0] = qb; ca.mode[0] = 4;
    ca.A[1] = encb; ca.Bt[1] = wtp[5]; ca.bias[1] = ca_kb; ca.O1[1] = kb; ca.mode[1] = 4;
    ca.A[2] = encb; ca.Bt[2] = wtp[6]; ca.bias[2] = ca_vb; ca.O1[2] = vt; ca.mode[2] = 2;

    dim3 blk(256);
    dim3 gqkv(8, 32, 3);
    dim3 g64(8, 64);      // BM=64 GEMMs (proj, FF2): 512 blocks
    dim3 gff1(16, 32);    // FF1 (BM=128, BN=128): 512 blocks
    dim3 gattn(32, 16, 2);
    dim3 gln(1024);

    prep<<<2048 + jb.cum[10], blk, 0, stream>>>(x, enc, xb, encb, jb);

    // ---- self-attention ----
    qkv_gemm<<<gqkv, blk, 0, stream>>>(sa);
    attn_mfma<<<gattn, blk, 0, stream>>>(qb, kb, vt, po0, po1, pl);
    attn_combine<<<1024, blk, 0, stream>>>(po0, po1, pl, attnb);
    gemm_bf16<64, 64, 4><<<g64, blk, 0, stream>>>(attnb, wtp[3], sa_ob, nullptr, projb, 4096, 512, 512);
    add_ln<false, true, false, true><<<gln, blk, 0, stream>>>(x, projb, ln0_g, ln0_b, nullptr, x1b);

    // ---- cross-attention ----
    qkv_gemm<<<gqkv, blk, 0, stream>>>(ca);
    attn_mfma<<<gattn, blk, 0, stream>>>(qb, kb, vt, po0, po1, pl);
    attn_combine<<<1024, blk, 0, stream>>>(po0, po1, pl, attnb);
    gemm_bf16<64, 64, 4><<<g64, blk, 0, stream>>>(attnb, wtp[7], ca_ob, nullptr, projb, 4096, 512, 512);
    add_ln<true, true, false, true><<<gln, blk, 0, stream>>>(x1b, projb, ln1_g, ln1_b, nullptr, x2b);

    // ---- feed-forward ----
    gemm_bf16<128, 128, 3><<<gff1, blk, 0, stream>>>(x2b, wtp[8], ff_b1, nullptr, ffb, 4096, 2048, 512);
    gemm_bf16<64, 64, 4><<<g64, blk, 0, stream>>>(ffb, wtp[9], ff_b2, nullptr, projb, 4096, 512, 2048);
    add_ln<true, true, true, false><<<gln, blk, 0, stream>>>(x2b, projb, ln2_g, ln2_b, out, nullptr);
}

// Round 9
// 171.761 us; speedup vs baseline: 1.1237x; 1.1237x over previous
//
#include <hip/hip_runtime.h>
#include <math.h>

// ---------------------------------------------------------------------------
// Decoder block: B=2, S=2048, D=512, H=8, DK=64, FF=2048.
// Round 9: revert r8's cvt_pk asm + permuted Vt (both regressed); keep bf16
// proj/LN chain. New: truncation P->bf16 (bias cancels in o/l ratio) and
// bf16 partial-O buffers (halve attn epilogue + combine traffic).
// Fixed-max softmax; KV-split=2; dbuf K/V staging via global_load_lds.
// LDS tiles: [rows][64] bf16, XOR-16B swizzle (phys_short = col ^ ((row&7)*8)).
// ---------------------------------------------------------------------------

typedef __attribute__((ext_vector_type(8))) short short8;   // 8 bf16
typedef __attribute__((ext_vector_type(4))) float f32x4;

#define MFMA16(a, b, c) __builtin_amdgcn_mfma_f32_16x16x32_bf16((a), (b), (c), 0, 0, 0)

__device__ __forceinline__ unsigned short f2bf(float f) {
    unsigned int u = __float_as_uint(f);
    u += 0x7fffu + ((u >> 16) & 1u);          // RNE
    return (unsigned short)(u >> 16);
}
__device__ __forceinline__ float bf2f(unsigned short h) {
    return __uint_as_float(((unsigned int)h) << 16);
}
__device__ __forceinline__ void g2l16(const void* g, void* l) {
    __builtin_amdgcn_global_load_lds(
        (const __attribute__((address_space(1))) unsigned int*)g,
        (__attribute__((address_space(3))) unsigned int*)l, 16, 0, 0);
}
// swizzled short-index within a [rows][64]-short LDS tile
__device__ __forceinline__ int swz(int row, int col) {
    return row * 64 + (col ^ ((row & 7) * 8));
}
// XCD-chunked work remap (bijective: all grids are multiples of 8)
__device__ __forceinline__ void xcd_remap(int& bx, int& by, int& bz) {
    const int gx = gridDim.x, gy = gridDim.y;
    const int nwg = gx * gy * gridDim.z;
    const int flat = blockIdx.x + gx * (blockIdx.y + gy * blockIdx.z);
    const int s = (flat & 7) * (nwg >> 3) + (flat >> 3);
    bx = s % gx; const int t = s / gx; by = t % gy; bz = t / gy;
}

// ---------------- bf16 GEMM: C[M,N] = A[M,K] @ Bt[N,K]^T + bias ------------
// 4 waves, double-buffered global_load_lds.
// MODE: 0 = f32 out; 3 = bf16+ReLU; 4 = bf16.
template <int BM, int BN, int MODE>
__global__ __launch_bounds__(256, (BM == 64) ? 4 : (BN == 128 ? 2 : 3))
void gemm_bf16(
    const unsigned short* __restrict__ A, const unsigned short* __restrict__ Bt,
    const float* __restrict__ bias, float* __restrict__ Cf,
    unsigned short* __restrict__ O1,
    int M, int N, int K)
{
    __shared__ unsigned short As[2][BM * 64];
    __shared__ unsigned short Bs[2][BN * 64];
    const int tid = threadIdx.x, wv = tid >> 6, lane = tid & 63;
    const int l15 = lane & 15, l4 = lane >> 4;
    int bx, by, bz; xcd_remap(bx, by, bz);
    const int bm = by * BM, bn = bx * BN;
    constexpr int MI = (BM == 64) ? 1 : (BN == 128 ? 4 : 2);
    constexpr int AJ = (BM == 64) ? 2 : 4;
    constexpr int BJ = (BN == 128) ? 4 : 2;
    const int wrow = (BM == 64) ? wv * 16 : (BN == 128 ? (wv >> 1) * 64 : wv * 32);
    const int wcol = (BN == 128) ? (wv & 1) * 64 : 0;
    const int aw = (BM == 64) ? wv * 16 : wv * 32;   // A-staging base row
    const int bw = (BN == 128) ? wv * 32 : wv * 16;  // B-staging base row

    f32x4 acc[MI][4];
    #pragma unroll
    for (int i = 0; i < MI; ++i)
        #pragma unroll
        for (int j = 0; j < 4; ++j) acc[i][j] = (f32x4){0.f, 0.f, 0.f, 0.f};

    const int srow = lane >> 3;                       // 0..7 within 8-row chunk
    const int sch  = (lane & 7) ^ srow;               // inverse-swizzled 16B chunk
    const unsigned short* Asrc = A + (size_t)(bm + aw + srow) * K + sch * 8;
    const unsigned short* Bsrc = Bt + (size_t)(bn + bw + srow) * K + sch * 8;

    auto stage = [&](int buf, int k0) {
        #pragma unroll
        for (int j = 0; j < AJ; ++j)
            g2l16(Asrc + (size_t)j * 8 * K + k0, &As[buf][(aw + j * 8) * 64]);
        #pragma unroll
        for (int j = 0; j < BJ; ++j)
            g2l16(Bsrc + (size_t)j * 8 * K + k0, &Bs[buf][(bw + j * 8) * 64]);
    };

    stage(0, 0);
    __syncthreads();
    int cur = 0;
    for (int k0 = 0; k0 < K; k0 += 64) {
        if (k0 + 64 < K) stage(cur ^ 1, k0 + 64);
        #pragma unroll
        for (int kk = 0; kk < 2; ++kk) {
            const int kc = kk * 32 + l4 * 8;
            short8 af[MI], bfr[4];
            #pragma unroll
            for (int mi = 0; mi < MI; ++mi)
                af[mi] = *(const short8*)&As[cur][swz(wrow + mi * 16 + l15, kc)];
            #pragma unroll
            for (int nf = 0; nf < 4; ++nf)
                bfr[nf] = *(const short8*)&Bs[cur][swz(wcol + nf * 16 + l15, kc)];
            __builtin_amdgcn_s_setprio(1);
            #pragma unroll
            for (int mi = 0; mi < MI; ++mi)
                #pragma unroll
                for (int nf = 0; nf < 4; ++nf)
                    acc[mi][nf] = MFMA16(af[mi], bfr[nf], acc[mi][nf]);
            __builtin_amdgcn_s_setprio(0);
        }
        __syncthreads();
        cur ^= 1;
    }

    #pragma unroll
    for (int nf = 0; nf < 4; ++nf) {
        const int n = bn + wcol + nf * 16 + l15;
        const float bv = bias[n];
        #pragma unroll
        for (int mi = 0; mi < MI; ++mi) {
            const int m0 = bm + wrow + mi * 16 + l4 * 4;
            #pragma unroll
            for (int r = 0; r < 4; ++r) {
                float v = acc[mi][nf][r] + bv;
                size_t idx = (size_t)(m0 + r) * N + n;
                if (MODE == 0)      Cf[idx] = v;
                else if (MODE == 3) O1[idx] = f2bf(fmaxf(v, 0.f));
                else                O1[idx] = f2bf(v);
            }
        }
    }
}

// ---------------- merged QKV GEMM (3 jobs in one launch) -------------------
struct QKVArgs {
    const unsigned short* A[3];
    const unsigned short* Bt[3];
    const float* bias[3];
    unsigned short* O1[3];
    int mode[3];      // 4 = plain bf16 out; 2 = transposed Vt out
};
__global__ __launch_bounds__(256, 3) void qkv_gemm(QKVArgs ja)
{
    __shared__ unsigned short As[2][128 * 64];
    __shared__ unsigned short Bs[2][64 * 64];
    const int tid = threadIdx.x, wv = tid >> 6, lane = tid & 63;
    const int l15 = lane & 15, l4 = lane >> 4;
    int bx, by, bz; xcd_remap(bx, by, bz);
    const int bm = by * 128, bn = bx * 64;
    const unsigned short* A  = ja.A[bz];
    const unsigned short* Bt = ja.Bt[bz];
    const int mode = ja.mode[bz];

    f32x4 acc[2][4];
    #pragma unroll
    for (int i = 0; i < 2; ++i)
        #pragma unroll
        for (int j = 0; j < 4; ++j) acc[i][j] = (f32x4){0.f, 0.f, 0.f, 0.f};

    const int srow = lane >> 3, sch = (lane & 7) ^ srow;
    const unsigned short* Asrc = A + (size_t)(bm + wv * 32 + srow) * 512 + sch * 8;
    const unsigned short* Bsrc = Bt + (size_t)(bn + wv * 16 + srow) * 512 + sch * 8;

    auto stage = [&](int buf, int k0) {
        #pragma unroll
        for (int j = 0; j < 4; ++j)
            g2l16(Asrc + (size_t)j * 8 * 512 + k0, &As[buf][(wv * 32 + j * 8) * 64]);
        #pragma unroll
        for (int j = 0; j < 2; ++j)
            g2l16(Bsrc + (size_t)j * 8 * 512 + k0, &Bs[buf][(wv * 16 + j * 8) * 64]);
    };

    stage(0, 0);
    __syncthreads();
    int cur = 0;
    for (int k0 = 0; k0 < 512; k0 += 64) {
        if (k0 + 64 < 512) stage(cur ^ 1, k0 + 64);
        #pragma unroll
        for (int kk = 0; kk < 2; ++kk) {
            const int kc = kk * 32 + l4 * 8;
            short8 af[2], bfr[4];
            af[0] = *(const short8*)&As[cur][swz(wv * 32 + l15, kc)];
            af[1] = *(const short8*)&As[cur][swz(wv * 32 + 16 + l15, kc)];
            #pragma unroll
            for (int nf = 0; nf < 4; ++nf)
                bfr[nf] = *(const short8*)&Bs[cur][swz(nf * 16 + l15, kc)];
            __builtin_amdgcn_s_setprio(1);
            #pragma unroll
            for (int mi = 0; mi < 2; ++mi)
                #pragma unroll
                for (int nf = 0; nf < 4; ++nf)
                    acc[mi][nf] = MFMA16(af[mi], bfr[nf], acc[mi][nf]);
            __builtin_amdgcn_s_setprio(0);
        }
        __syncthreads();
        cur ^= 1;
    }

    #pragma unroll
    for (int nf = 0; nf < 4; ++nf) {
        const int n = bn + nf * 16 + l15;
        const float bv = ja.bias[bz][n];
        #pragma unroll
        for (int mi = 0; mi < 2; ++mi) {
            const int m0 = bm + wv * 32 + mi * 16 + l4 * 4;
            if (mode == 2) {
                ushort4 pk;
                pk.x = f2bf(acc[mi][nf][0] + bv);
                pk.y = f2bf(acc[mi][nf][1] + bv);
                pk.z = f2bf(acc[mi][nf][2] + bv);
                pk.w = f2bf(acc[mi][nf][3] + bv);
                const int hh = n >> 6, dd = n & 63, bb = m0 >> 11, key = m0 & 2047;
                *(ushort4*)(ja.O1[bz] + ((((size_t)bb * 8 + hh) * 64 + dd) * 2048 + key)) = pk;
            } else {
                #pragma unroll
                for (int r = 0; r < 4; ++r)
                    ja.O1[bz][(size_t)(m0 + r) * 512 + n] = f2bf(acc[mi][nf][r] + bv);
            }
        }
    }
}

// ---------------- MFMA flash attention, fixed-max, KV-split=2 --------------
// Qb/Kb: [B*S, 512] bf16 head-major cols. Vt: [b][h][d][2048] bf16.
// Partials: PO{0,1}[4096][512] bf16 raw o-sums; PL[2][16][2048] f32 l-sums.
// Grid (S/64, B*H, 2), block 256 (4 waves x 16 q-rows).
// Fixed-max softmax (bounded scores); P->bf16 by truncation (bias cancels
// in o/l); K/V double-buffered via global_load_lds.
__global__ __launch_bounds__(256, 2) void attn_mfma(
    const unsigned short* __restrict__ Qb, const unsigned short* __restrict__ Kb,
    const unsigned short* __restrict__ Vt,
    unsigned short* __restrict__ PO0, unsigned short* __restrict__ PO1,
    float* __restrict__ PL)
{
    __shared__ unsigned short KH[2][64 * 64];
    __shared__ unsigned short VT[2][64 * 64];   // [d][key]
    __shared__ unsigned short PS[64 * 64];      // P scratch (wave-private rows)

    const int tid = threadIdx.x, wv = tid >> 6, lane = tid & 63;
    const int l15 = lane & 15, l4 = lane >> 4;
    int bx, by, bz; xcd_remap(bx, by, bz);
    const int bh = by, b = bh >> 3, h = bh & 7;
    const int q0 = bx * 64;
    const int srow = lane >> 3;
    const int sch  = (lane & 7) ^ srow;
    const int kt0 = bz * 16, kt1 = kt0 + 16;

    // Q fragments direct from global (one-time strided gather)
    short8 qh[2];
    {
        const size_t qrow = (size_t)(b * 2048 + q0 + wv * 16 + l15) * 512 + h * 64;
        qh[0] = *(const short8*)(Qb + qrow + l4 * 8);
        qh[1] = *(const short8*)(Qb + qrow + 32 + l4 * 8);
    }

    const unsigned short* k_src  = Kb + (size_t)(b * 2048 + wv * 16 + srow) * 512 + h * 64 + sch * 8;
    const unsigned short* vt_src = Vt + (size_t)(bh * 64 + wv * 16 + srow) * 2048 + sch * 8;

    auto stageKV = [&](int buf, int kt) {
        const size_t k0 = (size_t)kt * 64;
        #pragma unroll
        for (int j = 0; j < 2; ++j) {
            g2l16(k_src + (k0 + j * 8) * 512, &KH[buf][(wv * 16 + j * 8) * 64]);
            g2l16(vt_src + k0 + (size_t)j * 8 * 2048, &VT[buf][(wv * 16 + j * 8) * 64]);
        }
    };

    f32x4 o[4], lacc;
    #pragma unroll
    for (int i = 0; i < 4; ++i) o[i] = (f32x4){0.f, 0.f, 0.f, 0.f};
    lacc = (f32x4){0.f, 0.f, 0.f, 0.f};

    const short one_s = (short)(l15 == 0 ? 0x3F80 : 0);     // bf16 1.0 in col 0
    const short8 oneb = {one_s, one_s, one_s, one_s, one_s, one_s, one_s, one_s};

    stageKV(0, kt0);
    __syncthreads();
    int cur = 0;
    for (int kt = kt0; kt < kt1; ++kt) {
        if (kt + 1 < kt1) stageKV(cur ^ 1, kt + 1);   // prefetch under compute

        // QK^T: wave's 16 q-rows x 64 keys (plain bf16)
        f32x4 s[4];
        __builtin_amdgcn_s_setprio(1);
        #pragma unroll
        for (int f = 0; f < 4; ++f) {
            s[f] = (f32x4){0.f, 0.f, 0.f, 0.f};
            #pragma unroll
            for (int kk = 0; kk < 2; ++kk) {
                short8 kbf = *(const short8*)&KH[cur][swz(f * 16 + l15, kk * 32 + l4 * 8)];
                s[f] = MFMA16(qh[kk], kbf, s[f]);
            }
        }
        __builtin_amdgcn_s_setprio(0);

        // P = exp(floor(s/8)), fixed max 0; truncation to bf16 (1 op)
        #pragma unroll
        for (int f = 0; f < 4; ++f)
            #pragma unroll
            for (int r = 0; r < 4; ++r)
                PS[swz(wv * 16 + l4 * 4 + r, f * 16 + l15)] =
                    (unsigned short)(__float_as_uint(__expf(floorf(s[f][r] * 0.125f))) >> 16);

        short8 pa[2];
        pa[0] = *(const short8*)&PS[swz(wv * 16 + l15, l4 * 8)];
        pa[1] = *(const short8*)&PS[swz(wv * 16 + l15, 32 + l4 * 8)];

        __builtin_amdgcn_s_setprio(1);
        lacc = MFMA16(pa[0], oneb, lacc);     // row-sum via ones column
        lacc = MFMA16(pa[1], oneb, lacc);
        #pragma unroll
        for (int df = 0; df < 4; ++df) {
            #pragma unroll
            for (int kk = 0; kk < 2; ++kk) {
                short8 vb = *(const short8*)&VT[cur][swz(df * 16 + l15, kk * 32 + l4 * 8)];
                o[df] = MFMA16(pa[kk], vb, o[df]);
            }
        }
        __builtin_amdgcn_s_setprio(0);
        __syncthreads();                      // drain prefetch + readers done
        cur ^= 1;
    }

    // epilogue: bf16 partial o + f32 partial l
    unsigned short* PO = bz ? PO1 : PO0;
    #pragma unroll
    for (int df = 0; df < 4; ++df)
        #pragma unroll
        for (int r = 0; r < 4; ++r)
            PO[(size_t)(b * 2048 + q0 + wv * 16 + l4 * 4 + r) * 512 + h * 64 + df * 16 + l15]
                = f2bf(o[df][r]);
    if (l15 == 0) {
        #pragma unroll
        for (int r = 0; r < 4; ++r)
            PL[(bz * 16 + bh) * 2048 + q0 + wv * 16 + l4 * 4 + r] = lacc[r];
    }
}

// ---------------- combine: Ob = (po0+po1)/(l0+l1), bf16 --------------------
__global__ __launch_bounds__(256) void attn_combine(
    const unsigned short* __restrict__ po0, const unsigned short* __restrict__ po1,
    const float* __restrict__ pl, unsigned short* __restrict__ Ob)
{
    const size_t i = ((size_t)blockIdx.x * 256 + threadIdx.x) * 8;  // over 4096*512
    const int row = (int)(i >> 9), col = (int)(i & 511);
    const int b = row >> 11, q = row & 2047, h = col >> 6;
    const int bh = b * 8 + h;
    const float inv = 1.f / (pl[bh * 2048 + q] + pl[(16 + bh) * 2048 + q]);
    uint4 a = *(const uint4*)(po0 + i);
    uint4 c = *(const uint4*)(po1 + i);
    uint4 u;
    unsigned* ap = (unsigned*)&a; unsigned* cp = (unsigned*)&c; unsigned* up = (unsigned*)&u;
    #pragma unroll
    for (int w = 0; w < 4; ++w) {
        float lo = (bf2f(ap[w] & 0xffff) + bf2f(cp[w] & 0xffff)) * inv;
        float hi = (bf2f(ap[w] >> 16)   + bf2f(cp[w] >> 16))   * inv;
        up[w] = (unsigned)f2bf(lo) | ((unsigned)f2bf(hi) << 16);
    }
    *(uint4*)(Ob + i) = u;
}

// ---------------- fused residual add + LayerNorm (D=512) -------------------
// X: residual branch; R: projection branch. Types per template flags.
template <bool XBF, bool RBF, bool OUTF, bool OUTB>
__global__ __launch_bounds__(256) void add_ln(
    const void* __restrict__ Xv, const void* __restrict__ Rv,
    const float* __restrict__ g, const float* __restrict__ beta,
    float* __restrict__ OutF, unsigned short* __restrict__ OutB)
{
    const int row = blockIdx.x * 4 + (threadIdx.x >> 6);
    const int lane = threadIdx.x & 63;
    const int c0 = lane * 8;
    float xx[8], rr[8], v[8];
    if (XBF) {
        const unsigned short* xr = (const unsigned short*)Xv + (size_t)row * 512 + c0;
        uint4 u = *(const uint4*)xr;
        xx[0] = bf2f(u.x & 0xffff); xx[1] = bf2f(u.x >> 16);
        xx[2] = bf2f(u.y & 0xffff); xx[3] = bf2f(u.y >> 16);
        xx[4] = bf2f(u.z & 0xffff); xx[5] = bf2f(u.z >> 16);
        xx[6] = bf2f(u.w & 0xffff); xx[7] = bf2f(u.w >> 16);
    } else {
        const float* xr = (const float*)Xv + (size_t)row * 512 + c0;
        float4 a0 = *(const float4*)xr, a1 = *(const float4*)(xr + 4);
        xx[0] = a0.x; xx[1] = a0.y; xx[2] = a0.z; xx[3] = a0.w;
        xx[4] = a1.x; xx[5] = a1.y; xx[6] = a1.z; xx[7] = a1.w;
    }
    if (RBF) {
        const unsigned short* xr = (const unsigned short*)Rv + (size_t)row * 512 + c0;
        uint4 u = *(const uint4*)xr;
        rr[0] = bf2f(u.x & 0xffff); rr[1] = bf2f(u.x >> 16);
        rr[2] = bf2f(u.y & 0xffff); rr[3] = bf2f(u.y >> 16);
        rr[4] = bf2f(u.z & 0xffff); rr[5] = bf2f(u.z >> 16);
        rr[6] = bf2f(u.w & 0xffff); rr[7] = bf2f(u.w >> 16);
    } else {
        const float* xr = (const float*)Rv + (size_t)row * 512 + c0;
        float4 a0 = *(const float4*)xr, a1 = *(const float4*)(xr + 4);
        rr[0] = a0.x; rr[1] = a0.y; rr[2] = a0.z; rr[3] = a0.w;
        rr[4] = a1.x; rr[5] = a1.y; rr[6] = a1.z; rr[7] = a1.w;
    }
    float s = 0.f, s2 = 0.f;
    #pragma unroll
    for (int j = 0; j < 8; ++j) {
        v[j] = xx[j] + rr[j];
        s += v[j]; s2 += v[j] * v[j];
    }
    #pragma unroll
    for (int off = 1; off < 64; off <<= 1) {
        s  += __shfl_xor(s, off);
        s2 += __shfl_xor(s2, off);
    }
    const float mean = s * (1.f / 512.f);
    const float var = s2 * (1.f / 512.f) - mean * mean;
    const float rs = 1.f / sqrtf(var + 1e-5f);
    float ovals[8];
    const float* gg = g + c0; const float* bb = beta + c0;
    #pragma unroll
    for (int j = 0; j < 8; ++j) ovals[j] = (v[j] - mean) * rs * gg[j] + bb[j];
    if (OUTF) {
        float* po = OutF + (size_t)row * 512 + c0;
        *(float4*)po = (float4){ovals[0], ovals[1], ovals[2], ovals[3]};
        *(float4*)(po + 4) = (float4){ovals[4], ovals[5], ovals[6], ovals[7]};
    }
    if (OUTB) {
        uint4 u;
        u.x = (unsigned)f2bf(ovals[0]) | ((unsigned)f2bf(ovals[1]) << 16);
        u.y = (unsigned)f2bf(ovals[2]) | ((unsigned)f2bf(ovals[3]) << 16);
        u.z = (unsigned)f2bf(ovals[4]) | ((unsigned)f2bf(ovals[5]) << 16);
        u.w = (unsigned)f2bf(ovals[6]) | ((unsigned)f2bf(ovals[7]) << 16);
        *(uint4*)(OutB + (size_t)row * 512 + c0) = u;
    }
}

// ---------------- merged prep: conv x/enc -> bf16 + weight transposes ------
struct WTJobs {
    const float* src[10];
    unsigned short* dst[10];
    int K[10], N[10];
    int cum[11];
};
__global__ __launch_bounds__(256) void prep(
    const float* __restrict__ X, const float* __restrict__ E,
    unsigned short* __restrict__ Xb, unsigned short* __restrict__ Eb, WTJobs jb)
{
    __shared__ float T[32][33];
    const int bid = blockIdx.x;
    if (bid < 2048) {
        size_t i = ((size_t)bid * 256 + threadIdx.x) * 8;
        const float* src; unsigned short* dst; size_t off;
        if (i < 2097152) { src = X; dst = Xb; off = i; }
        else             { src = E; dst = Eb; off = i - 2097152; }
        float4 a = *(const float4*)(src + off), c = *(const float4*)(src + off + 4);
        uint4 u;
        u.x = (unsigned)f2bf(a.x) | ((unsigned)f2bf(a.y) << 16);
        u.y = (unsigned)f2bf(a.z) | ((unsigned)f2bf(a.w) << 16);
        u.z = (unsigned)f2bf(c.x) | ((unsigned)f2bf(c.y) << 16);
        u.w = (unsigned)f2bf(c.z) | ((unsigned)f2bf(c.w) << 16);
        *(uint4*)(dst + off) = u;
        return;
    }
    int wb = bid - 2048;
    int z = 0;
    while (wb >= jb.cum[z + 1]) ++z;
    const int lt = wb - jb.cum[z];
    const int K = jb.K[z], N = jb.N[z];
    const int ntx = N >> 5;
    const int tx = lt % ntx, ty = lt / ntx;
    const int r = threadIdx.x >> 3, c4 = (threadIdx.x & 7) * 4;
    float4 a = *(const float4*)(jb.src[z] + (size_t)(ty * 32 + r) * N + tx * 32 + c4);
    T[r][c4] = a.x; T[r][c4 + 1] = a.y; T[r][c4 + 2] = a.z; T[r][c4 + 3] = a.w;
    __syncthreads();
    ushort4 o;
    o.x = f2bf(T[c4][r]); o.y = f2bf(T[c4 + 1][r]);
    o.z = f2bf(T[c4 + 2][r]); o.w = f2bf(T[c4 + 3][r]);
    *(ushort4*)(jb.dst[z] + (size_t)(tx * 32 + r) * K + ty * 32 + c4) = o;
}

// ---------------------------------------------------------------------------
extern "C" void kernel_launch(void* const* d_in, const int* in_sizes, int n_in,
                              void* d_out, int out_size, void* d_ws, size_t ws_size,
                              hipStream_t stream)
{
    const float* x   = (const float*)d_in[0];
    const float* enc = (const float*)d_in[1];
    // d_in[2], d_in[3]: masks — dead in the reference.
    const float* Wp[8] = {(const float*)d_in[4],  (const float*)d_in[6],
                          (const float*)d_in[8],  (const float*)d_in[10],
                          (const float*)d_in[12], (const float*)d_in[14],
                          (const float*)d_in[16], (const float*)d_in[18]};
    const float* sa_qb = (const float*)d_in[5],  *sa_kb = (const float*)d_in[7];
    const float* sa_vb = (const float*)d_in[9],  *sa_ob = (const float*)d_in[11];
    const float* ca_qb = (const float*)d_in[13], *ca_kb = (const float*)d_in[15];
    const float* ca_vb = (const float*)d_in[17], *ca_ob = (const float*)d_in[19];
    const float* ff_W1 = (const float*)d_in[20], *ff_b1 = (const float*)d_in[21];
    const float* ff_W2 = (const float*)d_in[22], *ff_b2 = (const float*)d_in[23];
    const float* ln0_g = (const float*)d_in[24], *ln0_b = (const float*)d_in[25];
    const float* ln1_g = (const float*)d_in[26], *ln1_b = (const float*)d_in[27];
    const float* ln2_g = (const float*)d_in[28], *ln2_b = (const float*)d_in[29];

    char* base = (char*)d_ws;
    const size_t MB = 1u << 20;
    unsigned short* wt    = (unsigned short*)(base + 0 * MB);   // 8 MB
    unsigned short* xb    = (unsigned short*)(base + 8 * MB);   // 4 MB (reused as x2b)
    unsigned short* encb  = (unsigned short*)(base + 12 * MB);  // 4 MB
    unsigned short* x1b   = (unsigned short*)(base + 16 * MB);  // 4 MB
    unsigned short* attnb = (unsigned short*)(base + 20 * MB);  // 4 MB
    unsigned short* vt    = (unsigned short*)(base + 24 * MB);  // 4 MB
    unsigned short* qb    = (unsigned short*)(base + 28 * MB);  // 4 MB
    unsigned short* kb    = (unsigned short*)(base + 32 * MB);  // 4 MB
    float*          pl    = (float*)(base + 36 * MB);           // 256 KB
    unsigned short* projb = (unsigned short*)(base + 44 * MB);  // 4 MB bf16
    unsigned short* po0   = (unsigned short*)(base + 48 * MB);  // 4 MB bf16
    unsigned short* po1   = (unsigned short*)(base + 52 * MB);  // 4 MB bf16
    unsigned short* ffb   = qb;                                 // 16 MB overlay (28..44)
    unsigned short* x2b   = xb;                                 // overlay
    float* out = (float*)d_out;

    unsigned short* wtp[10];
    for (int i = 0; i < 8; ++i) wtp[i] = wt + (size_t)i * 262144;
    wtp[8] = wt + 8u * 262144;            // ff_W1t: [2048][512]
    wtp[9] = wt + 8u * 262144 + 1048576;  // ff_W2t: [512][2048]

    WTJobs jb;
    for (int i = 0; i < 8; ++i) { jb.src[i] = Wp[i]; jb.dst[i] = wtp[i]; jb.K[i] = 512; jb.N[i] = 512; }
    jb.src[8] = ff_W1; jb.dst[8] = wtp[8]; jb.K[8] = 512;  jb.N[8] = 2048;
    jb.src[9] = ff_W2; jb.dst[9] = wtp[9]; jb.K[9] = 2048; jb.N[9] = 512;
    jb.cum[0] = 0;
    for (int i = 0; i < 10; ++i)
        jb.cum[i + 1] = jb.cum[i] + (jb.N[i] >> 5) * (jb.K[i] >> 5);

    QKVArgs sa, ca;
    sa.A[0] = xb;  sa.Bt[0] = wtp[0]; sa.bias[0] = sa_qb; sa.O1[0] = qb; sa.mode[0] = 4;
    sa.A[1] = xb;  sa.Bt[1] = wtp[1]; sa.bias[1] = sa_kb; sa.O1[1] = kb; sa.mode[1] = 4;
    sa.A[2] = xb;  sa.Bt[2] = wtp[2]; sa.bias[2] = sa_vb; sa.O1[2] = vt; sa.mode[2] = 2;
    ca.A[0] = x1b;  ca.Bt[0] = wtp[4]; ca.bias[0] = ca_qb; ca.O1[0] = qb; ca.mode[0] = 4;
    ca.A[1] = encb; ca.Bt[1] = wtp[5]; ca.bias[1] = ca_kb; ca.O1[1] = kb; ca.mode[1] = 4;
    ca.A[2] = encb; ca.Bt[2] = wtp[6]; ca.bias[2] = ca_vb; ca.O1[2] = vt; ca.mode[2] = 2;

    dim3 blk(256);
    dim3 gqkv(8, 32, 3);
    dim3 g64(8, 64);      // BM=64 GEMMs (proj, FF2): 512 blocks
    dim3 gff1(16, 32);    // FF1 (BM=128, BN=128): 512 blocks
    dim3 gattn(32, 16, 2);
    dim3 gln(1024);

    prep<<<2048 + jb.cum[10], blk, 0, stream>>>(x, enc, xb, encb, jb);

    // ---- self-attention ----
    qkv_gemm<<<gqkv, blk, 0, stream>>>(sa);
    attn_mfma<<<gattn, blk, 0, stream>>>(qb, kb, vt, po0, po1, pl);
    attn_combine<<<1024, blk, 0, stream>>>(po0, po1, pl, attnb);
    gemm_bf16<64, 64, 4><<<g64, blk, 0, stream>>>(attnb, wtp[3], sa_ob, nullptr, projb, 4096, 512, 512);
    add_ln<false, true, false, true><<<gln, blk, 0, stream>>>(x, projb, ln0_g, ln0_b, nullptr, x1b);

    // ---- cross-attention ----
    qkv_gemm<<<gqkv, blk, 0, stream>>>(ca);
    attn_mfma<<<gattn, blk, 0, stream>>>(qb, kb, vt, po0, po1, pl);
    attn_combine<<<1024, blk, 0, stream>>>(po0, po1, pl, attnb);
    gemm_bf16<64, 64, 4><<<g64, blk, 0, stream>>>(attnb, wtp[7], ca_ob, nullptr, projb, 4096, 512, 512);
    add_ln<true, true, false, true><<<gln, blk, 0, stream>>>(x1b, projb, ln1_g, ln1_b, nullptr, x2b);

    // ---- feed-forward ----
    gemm_bf16<128, 128, 3><<<gff1, blk, 0, stream>>>(x2b, wtp[8], ff_b1, nullptr, ffb, 4096, 2048, 512);
    gemm_bf16<64, 64, 4><<<g64, blk, 0, stream>>>(ffb, wtp[9], ff_b2, nullptr, projb, 4096, 512, 2048);
    add_ln<true, true, true, false><<<gln, blk, 0, stream>>>(x2b, projb, ln2_g, ln2_b, out, nullptr);
}

// Round 10
// 170.016 us; speedup vs baseline: 1.1352x; 1.0103x over previous
//
#include <hip/hip_runtime.h>
#include <math.h>

// ---------------------------------------------------------------------------
// Decoder block: B=2, S=2048, D=512, H=8, DK=64, FF=2048.
// Round 10: Q pre-scaled by 1/8 (kills mul in attn P-path), FF2 split-K=2
// with f32 partials folded into a 3-input final LayerNorm (no extra launch).
// Fixed-max softmax; truncation P->bf16; KV-split=2; dbuf g2l16 staging.
// LDS tiles: [rows][64] bf16, XOR-16B swizzle (phys_short = col ^ ((row&7)*8)).
// ---------------------------------------------------------------------------

typedef __attribute__((ext_vector_type(8))) short short8;   // 8 bf16
typedef __attribute__((ext_vector_type(4))) float f32x4;

#define MFMA16(a, b, c) __builtin_amdgcn_mfma_f32_16x16x32_bf16((a), (b), (c), 0, 0, 0)

__device__ __forceinline__ unsigned short f2bf(float f) {
    unsigned int u = __float_as_uint(f);
    u += 0x7fffu + ((u >> 16) & 1u);          // RNE
    return (unsigned short)(u >> 16);
}
__device__ __forceinline__ float bf2f(unsigned short h) {
    return __uint_as_float(((unsigned int)h) << 16);
}
__device__ __forceinline__ void g2l16(const void* g, void* l) {
    __builtin_amdgcn_global_load_lds(
        (const __attribute__((address_space(1))) unsigned int*)g,
        (__attribute__((address_space(3))) unsigned int*)l, 16, 0, 0);
}
// swizzled short-index within a [rows][64]-short LDS tile
__device__ __forceinline__ int swz(int row, int col) {
    return row * 64 + (col ^ ((row & 7) * 8));
}
// XCD-chunked work remap (bijective: all grids are multiples of 8)
__device__ __forceinline__ void xcd_remap(int& bx, int& by, int& bz) {
    const int gx = gridDim.x, gy = gridDim.y;
    const int nwg = gx * gy * gridDim.z;
    const int flat = blockIdx.x + gx * (blockIdx.y + gy * blockIdx.z);
    const int s = (flat & 7) * (nwg >> 3) + (flat >> 3);
    bx = s % gx; const int t = s / gx; by = t % gy; bz = t / gy;
}

// ---------------- bf16 GEMM: C[M,N] = A[M,K] @ Bt[N,K]^T + bias ------------
// 4 waves, double-buffered global_load_lds.
// MODE: 0 = f32+bias; 3 = bf16+ReLU; 4 = bf16; 5 = f32 no-bias split-K=2
// (grid.z = 2, partial bz -> Cf / Cf2).
template <int BM, int BN, int MODE>
__global__ __launch_bounds__(256, (BM == 64) ? 4 : (BN == 128 ? 2 : 3))
void gemm_bf16(
    const unsigned short* __restrict__ A, const unsigned short* __restrict__ Bt,
    const float* __restrict__ bias, float* __restrict__ Cf, float* __restrict__ Cf2,
    unsigned short* __restrict__ O1,
    int M, int N, int K)
{
    __shared__ unsigned short As[2][BM * 64];
    __shared__ unsigned short Bs[2][BN * 64];
    const int tid = threadIdx.x, wv = tid >> 6, lane = tid & 63;
    const int l15 = lane & 15, l4 = lane >> 4;
    int bx, by, bz; xcd_remap(bx, by, bz);
    const int bm = by * BM, bn = bx * BN;
    constexpr int MI = (BM == 64) ? 1 : (BN == 128 ? 4 : 2);
    constexpr int AJ = (BM == 64) ? 2 : 4;
    constexpr int BJ = (BN == 128) ? 4 : 2;
    const int wrow = (BM == 64) ? wv * 16 : (BN == 128 ? (wv >> 1) * 64 : wv * 32);
    const int wcol = (BN == 128) ? (wv & 1) * 64 : 0;
    const int aw = (BM == 64) ? wv * 16 : wv * 32;   // A-staging base row
    const int bw = (BN == 128) ? wv * 32 : wv * 16;  // B-staging base row

    const int kbeg = (MODE == 5) ? bz * (K >> 1) : 0;
    const int kend = (MODE == 5) ? kbeg + (K >> 1) : K;

    f32x4 acc[MI][4];
    #pragma unroll
    for (int i = 0; i < MI; ++i)
        #pragma unroll
        for (int j = 0; j < 4; ++j) acc[i][j] = (f32x4){0.f, 0.f, 0.f, 0.f};

    const int srow = lane >> 3;                       // 0..7 within 8-row chunk
    const int sch  = (lane & 7) ^ srow;               // inverse-swizzled 16B chunk
    const unsigned short* Asrc = A + (size_t)(bm + aw + srow) * K + sch * 8;
    const unsigned short* Bsrc = Bt + (size_t)(bn + bw + srow) * K + sch * 8;

    auto stage = [&](int buf, int k0) {
        #pragma unroll
        for (int j = 0; j < AJ; ++j)
            g2l16(Asrc + (size_t)j * 8 * K + k0, &As[buf][(aw + j * 8) * 64]);
        #pragma unroll
        for (int j = 0; j < BJ; ++j)
            g2l16(Bsrc + (size_t)j * 8 * K + k0, &Bs[buf][(bw + j * 8) * 64]);
    };

    stage(0, kbeg);
    __syncthreads();
    int cur = 0;
    for (int k0 = kbeg; k0 < kend; k0 += 64) {
        if (k0 + 64 < kend) stage(cur ^ 1, k0 + 64);
        #pragma unroll
        for (int kk = 0; kk < 2; ++kk) {
            const int kc = kk * 32 + l4 * 8;
            short8 af[MI], bfr[4];
            #pragma unroll
            for (int mi = 0; mi < MI; ++mi)
                af[mi] = *(const short8*)&As[cur][swz(wrow + mi * 16 + l15, kc)];
            #pragma unroll
            for (int nf = 0; nf < 4; ++nf)
                bfr[nf] = *(const short8*)&Bs[cur][swz(wcol + nf * 16 + l15, kc)];
            __builtin_amdgcn_s_setprio(1);
            #pragma unroll
            for (int mi = 0; mi < MI; ++mi)
                #pragma unroll
                for (int nf = 0; nf < 4; ++nf)
                    acc[mi][nf] = MFMA16(af[mi], bfr[nf], acc[mi][nf]);
            __builtin_amdgcn_s_setprio(0);
        }
        __syncthreads();
        cur ^= 1;
    }

    float* Cout = (MODE == 5) ? (bz ? Cf2 : Cf) : Cf;
    #pragma unroll
    for (int nf = 0; nf < 4; ++nf) {
        const int n = bn + wcol + nf * 16 + l15;
        const float bv = (MODE == 5) ? 0.f : bias[n];
        #pragma unroll
        for (int mi = 0; mi < MI; ++mi) {
            const int m0 = bm + wrow + mi * 16 + l4 * 4;
            #pragma unroll
            for (int r = 0; r < 4; ++r) {
                float v = acc[mi][nf][r] + bv;
                size_t idx = (size_t)(m0 + r) * N + n;
                if (MODE == 0 || MODE == 5) Cout[idx] = v;
                else if (MODE == 3)         O1[idx] = f2bf(fmaxf(v, 0.f));
                else                        O1[idx] = f2bf(v);
            }
        }
    }
}

// ---------------- merged QKV GEMM (3 jobs in one launch) -------------------
struct QKVArgs {
    const unsigned short* A[3];
    const unsigned short* Bt[3];
    const float* bias[3];
    unsigned short* O1[3];
    int mode[3];      // 4 = plain bf16; 5 = bf16 scaled by 1/8 (Q); 2 = Vt out
};
__global__ __launch_bounds__(256, 3) void qkv_gemm(QKVArgs ja)
{
    __shared__ unsigned short As[2][128 * 64];
    __shared__ unsigned short Bs[2][64 * 64];
    const int tid = threadIdx.x, wv = tid >> 6, lane = tid & 63;
    const int l15 = lane & 15, l4 = lane >> 4;
    int bx, by, bz; xcd_remap(bx, by, bz);
    const int bm = by * 128, bn = bx * 64;
    const unsigned short* A  = ja.A[bz];
    const unsigned short* Bt = ja.Bt[bz];
    const int mode = ja.mode[bz];

    f32x4 acc[2][4];
    #pragma unroll
    for (int i = 0; i < 2; ++i)
        #pragma unroll
        for (int j = 0; j < 4; ++j) acc[i][j] = (f32x4){0.f, 0.f, 0.f, 0.f};

    const int srow = lane >> 3, sch = (lane & 7) ^ srow;
    const unsigned short* Asrc = A + (size_t)(bm + wv * 32 + srow) * 512 + sch * 8;
    const unsigned short* Bsrc = Bt + (size_t)(bn + wv * 16 + srow) * 512 + sch * 8;

    auto stage = [&](int buf, int k0) {
        #pragma unroll
        for (int j = 0; j < 4; ++j)
            g2l16(Asrc + (size_t)j * 8 * 512 + k0, &As[buf][(wv * 32 + j * 8) * 64]);
        #pragma unroll
        for (int j = 0; j < 2; ++j)
            g2l16(Bsrc + (size_t)j * 8 * 512 + k0, &Bs[buf][(wv * 16 + j * 8) * 64]);
    };

    stage(0, 0);
    __syncthreads();
    int cur = 0;
    for (int k0 = 0; k0 < 512; k0 += 64) {
        if (k0 + 64 < 512) stage(cur ^ 1, k0 + 64);
        #pragma unroll
        for (int kk = 0; kk < 2; ++kk) {
            const int kc = kk * 32 + l4 * 8;
            short8 af[2], bfr[4];
            af[0] = *(const short8*)&As[cur][swz(wv * 32 + l15, kc)];
            af[1] = *(const short8*)&As[cur][swz(wv * 32 + 16 + l15, kc)];
            #pragma unroll
            for (int nf = 0; nf < 4; ++nf)
                bfr[nf] = *(const short8*)&Bs[cur][swz(nf * 16 + l15, kc)];
            __builtin_amdgcn_s_setprio(1);
            #pragma unroll
            for (int mi = 0; mi < 2; ++mi)
                #pragma unroll
                for (int nf = 0; nf < 4; ++nf)
                    acc[mi][nf] = MFMA16(af[mi], bfr[nf], acc[mi][nf]);
            __builtin_amdgcn_s_setprio(0);
        }
        __syncthreads();
        cur ^= 1;
    }

    #pragma unroll
    for (int nf = 0; nf < 4; ++nf) {
        const int n = bn + nf * 16 + l15;
        const float bv = ja.bias[bz][n];
        #pragma unroll
        for (int mi = 0; mi < 2; ++mi) {
            const int m0 = bm + wv * 32 + mi * 16 + l4 * 4;
            if (mode == 2) {
                ushort4 pk;
                pk.x = f2bf(acc[mi][nf][0] + bv);
                pk.y = f2bf(acc[mi][nf][1] + bv);
                pk.z = f2bf(acc[mi][nf][2] + bv);
                pk.w = f2bf(acc[mi][nf][3] + bv);
                const int hh = n >> 6, dd = n & 63, bb = m0 >> 11, key = m0 & 2047;
                *(ushort4*)(ja.O1[bz] + ((((size_t)bb * 8 + hh) * 64 + dd) * 2048 + key)) = pk;
            } else {
                #pragma unroll
                for (int r = 0; r < 4; ++r) {
                    float v = acc[mi][nf][r] + bv;
                    if (mode == 5) v *= 0.125f;   // pre-scaled Q (exact pow2)
                    ja.O1[bz][(size_t)(m0 + r) * 512 + n] = f2bf(v);
                }
            }
        }
    }
}

// ---------------- MFMA flash attention, fixed-max, KV-split=2 --------------
// Qb: [B*S, 512] bf16 (pre-scaled by 1/8); Kb: [B*S, 512] bf16;
// Vt: [b][h][d][2048] bf16. Partials: PO{0,1}[4096][512] bf16; PL f32.
// Grid (S/64, B*H, 2), block 256 (4 waves x 16 q-rows).
// scores = floor(q/8 . k); P = exp(t) truncated to bf16.
__global__ __launch_bounds__(256, 2) void attn_mfma(
    const unsigned short* __restrict__ Qb, const unsigned short* __restrict__ Kb,
    const unsigned short* __restrict__ Vt,
    unsigned short* __restrict__ PO0, unsigned short* __restrict__ PO1,
    float* __restrict__ PL)
{
    __shared__ unsigned short KH[2][64 * 64];
    __shared__ unsigned short VT[2][64 * 64];   // [d][key]
    __shared__ unsigned short PS[64 * 64];      // P scratch (wave-private rows)

    const int tid = threadIdx.x, wv = tid >> 6, lane = tid & 63;
    const int l15 = lane & 15, l4 = lane >> 4;
    int bx, by, bz; xcd_remap(bx, by, bz);
    const int bh = by, b = bh >> 3, h = bh & 7;
    const int q0 = bx * 64;
    const int srow = lane >> 3;
    const int sch  = (lane & 7) ^ srow;
    const int kt0 = bz * 16, kt1 = kt0 + 16;

    // Q fragments direct from global (one-time strided gather)
    short8 qh[2];
    {
        const size_t qrow = (size_t)(b * 2048 + q0 + wv * 16 + l15) * 512 + h * 64;
        qh[0] = *(const short8*)(Qb + qrow + l4 * 8);
        qh[1] = *(const short8*)(Qb + qrow + 32 + l4 * 8);
    }

    const unsigned short* k_src  = Kb + (size_t)(b * 2048 + wv * 16 + srow) * 512 + h * 64 + sch * 8;
    const unsigned short* vt_src = Vt + (size_t)(bh * 64 + wv * 16 + srow) * 2048 + sch * 8;

    auto stageKV = [&](int buf, int kt) {
        const size_t k0 = (size_t)kt * 64;
        #pragma unroll
        for (int j = 0; j < 2; ++j) {
            g2l16(k_src + (k0 + j * 8) * 512, &KH[buf][(wv * 16 + j * 8) * 64]);
            g2l16(vt_src + k0 + (size_t)j * 8 * 2048, &VT[buf][(wv * 16 + j * 8) * 64]);
        }
    };

    f32x4 o[4], lacc;
    #pragma unroll
    for (int i = 0; i < 4; ++i) o[i] = (f32x4){0.f, 0.f, 0.f, 0.f};
    lacc = (f32x4){0.f, 0.f, 0.f, 0.f};

    const short one_s = (short)(l15 == 0 ? 0x3F80 : 0);     // bf16 1.0 in col 0
    const short8 oneb = {one_s, one_s, one_s, one_s, one_s, one_s, one_s, one_s};

    stageKV(0, kt0);
    __syncthreads();
    int cur = 0;
    for (int kt = kt0; kt < kt1; ++kt) {
        if (kt + 1 < kt1) stageKV(cur ^ 1, kt + 1);   // prefetch under compute

        // QK^T: wave's 16 q-rows x 64 keys (Q pre-scaled, so s = qk/8)
        f32x4 s[4];
        __builtin_amdgcn_s_setprio(1);
        #pragma unroll
        for (int f = 0; f < 4; ++f) {
            s[f] = (f32x4){0.f, 0.f, 0.f, 0.f};
            #pragma unroll
            for (int kk = 0; kk < 2; ++kk) {
                short8 kbf = *(const short8*)&KH[cur][swz(f * 16 + l15, kk * 32 + l4 * 8)];
                s[f] = MFMA16(qh[kk], kbf, s[f]);
            }
        }
        __builtin_amdgcn_s_setprio(0);

        // P = exp(floor(s)), fixed max 0; truncation to bf16
        #pragma unroll
        for (int f = 0; f < 4; ++f)
            #pragma unroll
            for (int r = 0; r < 4; ++r)
                PS[swz(wv * 16 + l4 * 4 + r, f * 16 + l15)] =
                    (unsigned short)(__float_as_uint(__expf(floorf(s[f][r]))) >> 16);

        short8 pa[2];
        pa[0] = *(const short8*)&PS[swz(wv * 16 + l15, l4 * 8)];
        pa[1] = *(const short8*)&PS[swz(wv * 16 + l15, 32 + l4 * 8)];

        __builtin_amdgcn_s_setprio(1);
        lacc = MFMA16(pa[0], oneb, lacc);     // row-sum via ones column
        lacc = MFMA16(pa[1], oneb, lacc);
        #pragma unroll
        for (int df = 0; df < 4; ++df) {
            #pragma unroll
            for (int kk = 0; kk < 2; ++kk) {
                short8 vb = *(const short8*)&VT[cur][swz(df * 16 + l15, kk * 32 + l4 * 8)];
                o[df] = MFMA16(pa[kk], vb, o[df]);
            }
        }
        __builtin_amdgcn_s_setprio(0);
        __syncthreads();                      // drain prefetch + readers done
        cur ^= 1;
    }

    // epilogue: bf16 partial o + f32 partial l
    unsigned short* PO = bz ? PO1 : PO0;
    #pragma unroll
    for (int df = 0; df < 4; ++df)
        #pragma unroll
        for (int r = 0; r < 4; ++r)
            PO[(size_t)(b * 2048 + q0 + wv * 16 + l4 * 4 + r) * 512 + h * 64 + df * 16 + l15]
                = f2bf(o[df][r]);
    if (l15 == 0) {
        #pragma unroll
        for (int r = 0; r < 4; ++r)
            PL[(bz * 16 + bh) * 2048 + q0 + wv * 16 + l4 * 4 + r] = lacc[r];
    }
}

// ---------------- combine: Ob = (po0+po1)/(l0+l1), bf16 --------------------
__global__ __launch_bounds__(256) void attn_combine(
    const unsigned short* __restrict__ po0, const unsigned short* __restrict__ po1,
    const float* __restrict__ pl, unsigned short* __restrict__ Ob)
{
    const size_t i = ((size_t)blockIdx.x * 256 + threadIdx.x) * 8;  // over 4096*512
    const int row = (int)(i >> 9), col = (int)(i & 511);
    const int b = row >> 11, q = row & 2047, h = col >> 6;
    const int bh = b * 8 + h;
    const float inv = 1.f / (pl[bh * 2048 + q] + pl[(16 + bh) * 2048 + q]);
    uint4 a = *(const uint4*)(po0 + i);
    uint4 c = *(const uint4*)(po1 + i);
    uint4 u;
    unsigned* ap = (unsigned*)&a; unsigned* cp = (unsigned*)&c; unsigned* up = (unsigned*)&u;
    #pragma unroll
    for (int w = 0; w < 4; ++w) {
        float lo = (bf2f(ap[w] & 0xffff) + bf2f(cp[w] & 0xffff)) * inv;
        float hi = (bf2f(ap[w] >> 16)   + bf2f(cp[w] >> 16))   * inv;
        up[w] = (unsigned)f2bf(lo) | ((unsigned)f2bf(hi) << 16);
    }
    *(uint4*)(Ob + i) = u;
}

// ---------------- fused residual add + LayerNorm (D=512) -------------------
// out = LN(X + R [+ R2 + rb]).  X bf16/f32 per XBF; R bf16/f32 per RBF;
// R2/rb f32 (enabled by HASR2).
template <bool XBF, bool RBF, bool HASR2, bool OUTF, bool OUTB>
__global__ __launch_bounds__(256) void add_ln(
    const void* __restrict__ Xv, const void* __restrict__ Rv,
    const float* __restrict__ R2v, const float* __restrict__ rb,
    const float* __restrict__ g, const float* __restrict__ beta,
    float* __restrict__ OutF, unsigned short* __restrict__ OutB)
{
    const int row = blockIdx.x * 4 + (threadIdx.x >> 6);
    const int lane = threadIdx.x & 63;
    const int c0 = lane * 8;
    float xx[8], rr[8], v[8];
    if (XBF) {
        const unsigned short* xr = (const unsigned short*)Xv + (size_t)row * 512 + c0;
        uint4 u = *(const uint4*)xr;
        xx[0] = bf2f(u.x & 0xffff); xx[1] = bf2f(u.x >> 16);
        xx[2] = bf2f(u.y & 0xffff); xx[3] = bf2f(u.y >> 16);
        xx[4] = bf2f(u.z & 0xffff); xx[5] = bf2f(u.z >> 16);
        xx[6] = bf2f(u.w & 0xffff); xx[7] = bf2f(u.w >> 16);
    } else {
        const float* xr = (const float*)Xv + (size_t)row * 512 + c0;
        float4 a0 = *(const float4*)xr, a1 = *(const float4*)(xr + 4);
        xx[0] = a0.x; xx[1] = a0.y; xx[2] = a0.z; xx[3] = a0.w;
        xx[4] = a1.x; xx[5] = a1.y; xx[6] = a1.z; xx[7] = a1.w;
    }
    if (RBF) {
        const unsigned short* xr = (const unsigned short*)Rv + (size_t)row * 512 + c0;
        uint4 u = *(const uint4*)xr;
        rr[0] = bf2f(u.x & 0xffff); rr[1] = bf2f(u.x >> 16);
        rr[2] = bf2f(u.y & 0xffff); rr[3] = bf2f(u.y >> 16);
        rr[4] = bf2f(u.z & 0xffff); rr[5] = bf2f(u.z >> 16);
        rr[6] = bf2f(u.w & 0xffff); rr[7] = bf2f(u.w >> 16);
    } else {
        const float* xr = (const float*)Rv + (size_t)row * 512 + c0;
        float4 a0 = *(const float4*)xr, a1 = *(const float4*)(xr + 4);
        rr[0] = a0.x; rr[1] = a0.y; rr[2] = a0.z; rr[3] = a0.w;
        rr[4] = a1.x; rr[5] = a1.y; rr[6] = a1.z; rr[7] = a1.w;
    }
    if (HASR2) {
        const float* r2 = R2v + (size_t)row * 512 + c0;
        float4 a0 = *(const float4*)r2, a1 = *(const float4*)(r2 + 4);
        const float* rbp = rb + c0;
        rr[0] += a0.x + rbp[0]; rr[1] += a0.y + rbp[1];
        rr[2] += a0.z + rbp[2]; rr[3] += a0.w + rbp[3];
        rr[4] += a1.x + rbp[4]; rr[5] += a1.y + rbp[5];
        rr[6] += a1.z + rbp[6]; rr[7] += a1.w + rbp[7];
    }
    float s = 0.f, s2 = 0.f;
    #pragma unroll
    for (int j = 0; j < 8; ++j) {
        v[j] = xx[j] + rr[j];
        s += v[j]; s2 += v[j] * v[j];
    }
    #pragma unroll
    for (int off = 1; off < 64; off <<= 1) {
        s  += __shfl_xor(s, off);
        s2 += __shfl_xor(s2, off);
    }
    const float mean = s * (1.f / 512.f);
    const float var = s2 * (1.f / 512.f) - mean * mean;
    const float rs = 1.f / sqrtf(var + 1e-5f);
    float ovals[8];
    const float* gg = g + c0; const float* bb = beta + c0;
    #pragma unroll
    for (int j = 0; j < 8; ++j) ovals[j] = (v[j] - mean) * rs * gg[j] + bb[j];
    if (OUTF) {
        float* po = OutF + (size_t)row * 512 + c0;
        *(float4*)po = (float4){ovals[0], ovals[1], ovals[2], ovals[3]};
        *(float4*)(po + 4) = (float4){ovals[4], ovals[5], ovals[6], ovals[7]};
    }
    if (OUTB) {
        uint4 u;
        u.x = (unsigned)f2bf(ovals[0]) | ((unsigned)f2bf(ovals[1]) << 16);
        u.y = (unsigned)f2bf(ovals[2]) | ((unsigned)f2bf(ovals[3]) << 16);
        u.z = (unsigned)f2bf(ovals[4]) | ((unsigned)f2bf(ovals[5]) << 16);
        u.w = (unsigned)f2bf(ovals[6]) | ((unsigned)f2bf(ovals[7]) << 16);
        *(uint4*)(OutB + (size_t)row * 512 + c0) = u;
    }
}

// ---------------- merged prep: conv x/enc -> bf16 + weight transposes ------
struct WTJobs {
    const float* src[10];
    unsigned short* dst[10];
    int K[10], N[10];
    int cum[11];
};
__global__ __launch_bounds__(256) void prep(
    const float* __restrict__ X, const float* __restrict__ E,
    unsigned short* __restrict__ Xb, unsigned short* __restrict__ Eb, WTJobs jb)
{
    __shared__ float T[32][33];
    const int bid = blockIdx.x;
    if (bid < 2048) {
        size_t i = ((size_t)bid * 256 + threadIdx.x) * 8;
        const float* src; unsigned short* dst; size_t off;
        if (i < 2097152) { src = X; dst = Xb; off = i; }
        else             { src = E; dst = Eb; off = i - 2097152; }
        float4 a = *(const float4*)(src + off), c = *(const float4*)(src + off + 4);
        uint4 u;
        u.x = (unsigned)f2bf(a.x) | ((unsigned)f2bf(a.y) << 16);
        u.y = (unsigned)f2bf(a.z) | ((unsigned)f2bf(a.w) << 16);
        u.z = (unsigned)f2bf(c.x) | ((unsigned)f2bf(c.y) << 16);
        u.w = (unsigned)f2bf(c.z) | ((unsigned)f2bf(c.w) << 16);
        *(uint4*)(dst + off) = u;
        return;
    }
    int wb = bid - 2048;
    int z = 0;
    while (wb >= jb.cum[z + 1]) ++z;
    const int lt = wb - jb.cum[z];
    const int K = jb.K[z], N = jb.N[z];
    const int ntx = N >> 5;
    const int tx = lt % ntx, ty = lt / ntx;
    const int r = threadIdx.x >> 3, c4 = (threadIdx.x & 7) * 4;
    float4 a = *(const float4*)(jb.src[z] + (size_t)(ty * 32 + r) * N + tx * 32 + c4);
    T[r][c4] = a.x; T[r][c4 + 1] = a.y; T[r][c4 + 2] = a.z; T[r][c4 + 3] = a.w;
    __syncthreads();
    ushort4 o;
    o.x = f2bf(T[c4][r]); o.y = f2bf(T[c4 + 1][r]);
    o.z = f2bf(T[c4 + 2][r]); o.w = f2bf(T[c4 + 3][r]);
    *(ushort4*)(jb.dst[z] + (size_t)(tx * 32 + r) * K + ty * 32 + c4) = o;
}

// ---------------------------------------------------------------------------
extern "C" void kernel_launch(void* const* d_in, const int* in_sizes, int n_in,
                              void* d_out, int out_size, void* d_ws, size_t ws_size,
                              hipStream_t stream)
{
    const float* x   = (const float*)d_in[0];
    const float* enc = (const float*)d_in[1];
    // d_in[2], d_in[3]: masks — dead in the reference.
    const float* Wp[8] = {(const float*)d_in[4],  (const float*)d_in[6],
                          (const float*)d_in[8],  (const float*)d_in[10],
                          (const float*)d_in[12], (const float*)d_in[14],
                          (const float*)d_in[16], (const float*)d_in[18]};
    const float* sa_qb = (const float*)d_in[5],  *sa_kb = (const float*)d_in[7];
    const float* sa_vb = (const float*)d_in[9],  *sa_ob = (const float*)d_in[11];
    const float* ca_qb = (const float*)d_in[13], *ca_kb = (const float*)d_in[15];
    const float* ca_vb = (const float*)d_in[17], *ca_ob = (const float*)d_in[19];
    const float* ff_W1 = (const float*)d_in[20], *ff_b1 = (const float*)d_in[21];
    const float* ff_W2 = (const float*)d_in[22], *ff_b2 = (const float*)d_in[23];
    const float* ln0_g = (const float*)d_in[24], *ln0_b = (const float*)d_in[25];
    const float* ln1_g = (const float*)d_in[26], *ln1_b = (const float*)d_in[27];
    const float* ln2_g = (const float*)d_in[28], *ln2_b = (const float*)d_in[29];

    char* base = (char*)d_ws;
    const size_t MB = 1u << 20;
    unsigned short* wt    = (unsigned short*)(base + 0 * MB);   // 8 MB
    unsigned short* xb    = (unsigned short*)(base + 8 * MB);   // 4 MB (reused as x2b)
    unsigned short* encb  = (unsigned short*)(base + 12 * MB);  // 4 MB
    unsigned short* x1b   = (unsigned short*)(base + 16 * MB);  // 4 MB
    unsigned short* attnb = (unsigned short*)(base + 20 * MB);  // 4 MB
    unsigned short* vt    = (unsigned short*)(base + 24 * MB);  // 4 MB
    unsigned short* qb    = (unsigned short*)(base + 28 * MB);  // 4 MB
    unsigned short* kb    = (unsigned short*)(base + 32 * MB);  // 4 MB
    float*          pl    = (float*)(base + 36 * MB);           // 256 KB
    unsigned short* po0   = (unsigned short*)(base + 40 * MB);  // 4 MB bf16
    unsigned short* po1   = (unsigned short*)(base + 44 * MB);  // 4 MB bf16
    unsigned short* projb = (unsigned short*)(base + 28 * MB);  // overlay qb (dead post-attn)
    float*          g0    = (float*)(base + 40 * MB);           // 8 MB (overlay po0/po1, dead)
    float*          g1    = (float*)(base + 48 * MB);           // 8 MB (total 56 MB)
    unsigned short* ffb   = attnb;                              // 16 MB overlay (20..36, FF phase)
    unsigned short* x2b   = xb;                                 // overlay
    float* out = (float*)d_out;

    unsigned short* wtp[10];
    for (int i = 0; i < 8; ++i) wtp[i] = wt + (size_t)i * 262144;
    wtp[8] = wt + 8u * 262144;            // ff_W1t: [2048][512]
    wtp[9] = wt + 8u * 262144 + 1048576;  // ff_W2t: [512][2048]

    WTJobs jb;
    for (int i = 0; i < 8; ++i) { jb.src[i] = Wp[i]; jb.dst[i] = wtp[i]; jb.K[i] = 512; jb.N[i] = 512; }
    jb.src[8] = ff_W1; jb.dst[8] = wtp[8]; jb.K[8] = 512;  jb.N[8] = 2048;
    jb.src[9] = ff_W2; jb.dst[9] = wtp[9]; jb.K[9] = 2048; jb.N[9] = 512;
    jb.cum[0] = 0;
    for (int i = 0; i < 10; ++i)
        jb.cum[i + 1] = jb.cum[i] + (jb.N[i] >> 5) * (jb.K[i] >> 5);

    QKVArgs sa, ca;
    sa.A[0] = xb;  sa.Bt[0] = wtp[0]; sa.bias[0] = sa_qb; sa.O1[0] = qb; sa.mode[0] = 5;
    sa.A[1] = xb;  sa.Bt[1] = wtp[1]; sa.bias[1] = sa_kb; sa.O1[1] = kb; sa.mode[1] = 4;
    sa.A[2] = xb;  sa.Bt[2] = wtp[2]; sa.bias[2] = sa_vb; sa.O1[2] = vt; sa.mode[2] = 2;
    ca.A[0] = x1b;  ca.Bt[0] = wtp[4]; ca.bias[0] = ca_qb; ca.O1[0] = qb; ca.mode[0] = 5;
    ca.A[1] = encb; ca.Bt[1] = wtp[5]; ca.bias[1] = ca_kb; ca.O1[1] = kb; ca.mode[1] = 4;
    ca.A[2] = encb; ca.Bt[2] = wtp[6]; ca.bias[2] = ca_vb; ca.O1[2] = vt; ca.mode[2] = 2;

    dim3 blk(256);
    dim3 gqkv(8, 32, 3);
    dim3 g64(8, 64);       // BM=64 GEMMs (proj): 512 blocks
    dim3 gff1(16, 32);     // FF1 (BM=128, BN=128): 512 blocks
    dim3 gff2(8, 64, 2);   // FF2 split-K=2: 1024 blocks
    dim3 gattn(32, 16, 2);
    dim3 gln(1024);

    prep<<<2048 + jb.cum[10], blk, 0, stream>>>(x, enc, xb, encb, jb);

    // ---- self-attention ----
    qkv_gemm<<<gqkv, blk, 0, stream>>>(sa);
    attn_mfma<<<gattn, blk, 0, stream>>>(qb, kb, vt, po0, po1, pl);
    attn_combine<<<1024, blk, 0, stream>>>(po0, po1, pl, attnb);
    gemm_bf16<64, 64, 4><<<g64, blk, 0, stream>>>(attnb, wtp[3], sa_ob, nullptr, nullptr, projb, 4096, 512, 512);
    add_ln<false, true, false, false, true><<<gln, blk, 0, stream>>>(x, projb, nullptr, nullptr, ln0_g, ln0_b, nullptr, x1b);

    // ---- cross-attention ----
    qkv_gemm<<<gqkv, blk, 0, stream>>>(ca);
    attn_mfma<<<gattn, blk, 0, stream>>>(qb, kb, vt, po0, po1, pl);
    attn_combine<<<1024, blk, 0, stream>>>(po0, po1, pl, attnb);
    gemm_bf16<64, 64, 4><<<g64, blk, 0, stream>>>(attnb, wtp[7], ca_ob, nullptr, nullptr, projb, 4096, 512, 512);
    add_ln<true, true, false, false, true><<<gln, blk, 0, stream>>>(x1b, projb, nullptr, nullptr, ln1_g, ln1_b, nullptr, x2b);

    // ---- feed-forward ----
    gemm_bf16<128, 128, 3><<<gff1, blk, 0, stream>>>(x2b, wtp[8], ff_b1, nullptr, nullptr, ffb, 4096, 2048, 512);
    gemm_bf16<64, 64, 5><<<gff2, blk, 0, stream>>>(ffb, wtp[9], nullptr, g0, g1, nullptr, 4096, 512, 2048);
    add_ln<true, false, true, true, false><<<gln, blk, 0, stream>>>(x2b, g0, g1, ff_b2, ln2_g, ln2_b, out, nullptr);
}